// Round 8
// baseline (287.539 us; speedup 1.0000x reference)
//
#include <hip/hip_runtime.h>
#include <math.h>

#define N_COMP 20000
#define N_MEAS 64
#define LOG2PI 1.8378770664093453
#define LOGPD  (-0.020202707317519466)   /* log(0.98) */
#define CLUTTER 1e-4
#define NBLK_STATS 80                    /* 80*256 = 20480 >= 20000 */
#define NBLK_N 79                        /* ceil(20000/256) */
#define COV_F4 (N_COMP * 36 / 4)         /* 180000 float4 per measurement cov slice */
#define CHUNK_F4 1024                    /* 16 KB dest run per block */
#define NCHUNK ((COV_F4 + CHUNK_F4 - 1) / CHUNK_F4)   /* 176 */

typedef float f32x4 __attribute__((ext_vector_type(4)));

struct Loc6 { double v[6]; };            // bw * exp(-k^2/18), k=0..5 (host-computed)

// ---------------------------------------------------------------------------
// Kernel 1: per-block partial sums for empirical covariance (double).
// ---------------------------------------------------------------------------
__global__ __launch_bounds__(256) void stats1_kernel(const float* __restrict__ pm,
                                                     double* __restrict__ partials)
{
    int n = blockIdx.x * 256 + threadIdx.x;
    float v[6] = {0.f, 0.f, 0.f, 0.f, 0.f, 0.f};
    if (n < N_COMP) {
        const float2* p2 = (const float2*)(pm + (size_t)n * 6);
        float2 a = p2[0], b = p2[1], c = p2[2];
        v[0] = a.x; v[1] = a.y; v[2] = b.x; v[3] = b.y; v[4] = c.x; v[5] = c.y;
    }
    double s[27];
#pragma unroll
    for (int i = 0; i < 6; i++) s[i] = (double)v[i];
    int idx = 6;
#pragma unroll
    for (int i = 0; i < 6; i++)
#pragma unroll
        for (int j = i; j < 6; j++) s[idx++] = (double)v[i] * (double)v[j];

#pragma unroll
    for (int i = 0; i < 27; i++)
        for (int off = 32; off; off >>= 1) s[i] += __shfl_down(s[i], off);

    __shared__ double sd[27 * 4];
    int wid = threadIdx.x >> 6, lane = threadIdx.x & 63;
    if (lane == 0)
#pragma unroll
        for (int i = 0; i < 27; i++) sd[i * 4 + wid] = s[i];
    __syncthreads();
    if (threadIdx.x < 27) {
        int i = threadIdx.x;
        partials[(size_t)blockIdx.x * 27 + i] =
            sd[i * 4] + sd[i * 4 + 1] + sd[i * 4 + 2] + sd[i * 4 + 3];
    }
}

// ---------------------------------------------------------------------------
// Kernel 2: per-component linearization, with stats2 folded in: each block
// redundantly reduces the 80x27 partials (17 KB, L2-hit after first touch)
// and computes the localized bandwidth-scaled P inline. Writes SoA params
// (param4[i][n], coalesced) and the m=0 covariance slice via LDS transpose.
// ---------------------------------------------------------------------------
__global__ __launch_bounds__(64) void compA_kernel(
    const float* __restrict__ pm, const float* __restrict__ wts,
    const float* __restrict__ R, const double* __restrict__ partials,
    Loc6 bwloc, f32x4* __restrict__ param4, float* __restrict__ out3)
{
    __shared__ float sP[36];
    __shared__ float sR[9];
    __shared__ double tot[27];
    __shared__ float scov[64 * 36];
    int t = threadIdx.x;
    if (t < 27) {
        double a = 0.0;
        for (int b = 0; b < NBLK_STATS; b++) a += partials[(size_t)b * 27 + t];
        tot[t] = a;
    } else if (t >= 32 && t < 41) {
        sR[t - 32] = R[t - 32];
    }
    __syncthreads();
    if (t == 0) {
        double mean[6];
        for (int i = 0; i < 6; i++) mean[i] = tot[i] / (double)N_COMP;
        int idx = 6;
        for (int i = 0; i < 6; i++)
            for (int j = i; j < 6; j++) {
                double c = (tot[idx++] - (double)N_COMP * mean[i] * mean[j]) /
                           (double)(N_COMP - 1);
                float pv = (float)(c * bwloc.v[j - i]);   // bw * cov * loc(|i-j|)
                sP[i * 6 + j] = pv;
                sP[j * 6 + i] = pv;
            }
    }
    __syncthreads();

    int n = blockIdx.x * 64 + t;
    bool valid = n < N_COMP;

    if (valid) {
        const float2* pmv = (const float2*)(pm + (size_t)n * 6);
        float2 m01 = pmv[0], m23 = pmv[1];
        float x = m01.x, y = m01.y, z = m23.x;
        float rxy2 = x * x + y * y;
        float r2 = rxy2 + z * z;
        float r = sqrtf(r2);
        float rxy = sqrtf(rxy2);

        float yb0 = r;
        float yb1 = atan2f(y, x);
        float yb2 = asinf(z / r);

        // Analytic Jacobian of h (position columns only)
        float h[3][3];
        h[0][0] = x / r;      h[0][1] = y / r;      h[0][2] = z / r;
        h[1][0] = -y / rxy2;  h[1][1] = x / rxy2;   h[1][2] = 0.f;
        float inv_r2rxy = 1.f / (r2 * rxy);
        h[2][0] = -x * z * inv_r2rxy;
        h[2][1] = -y * z * inv_r2rxy;
        h[2][2] = rxy / r2;

        // PHt[i][k] = sum_j P[i][j] * H[k][j]
        float PHt[6][3];
#pragma unroll
        for (int i = 0; i < 6; i++)
#pragma unroll
            for (int k = 0; k < 3; k++)
                PHt[i][k] = sP[i*6+0] * h[k][0] + sP[i*6+1] * h[k][1] + sP[i*6+2] * h[k][2];

        // S = H*PHt + R; invert 3x3 in double (condition ~6e6)
        double Sm[3][3];
#pragma unroll
        for (int k = 0; k < 3; k++)
#pragma unroll
            for (int l = 0; l < 3; l++) {
                double acc = (double)sR[k * 3 + l];
#pragma unroll
                for (int i = 0; i < 3; i++) acc += (double)h[k][i] * (double)PHt[i][l];
                Sm[k][l] = acc;
            }
        double a = Sm[0][0], b = Sm[0][1], c = Sm[0][2];
        double d = Sm[1][1], e = Sm[1][2], f = Sm[2][2];
        double A = d * f - e * e;
        double B = c * e - b * f;
        double C = b * e - c * d;
        double det = a * A + b * B + c * C;
        double invdet = 1.0 / det;
        double si_[3][3];
        si_[0][0] = A * invdet;  si_[0][1] = B * invdet;  si_[0][2] = C * invdet;
        si_[1][1] = (a * f - c * c) * invdet;
        si_[1][2] = (b * c - a * e) * invdet;
        si_[2][2] = (a * d - b * b) * invdet;
        si_[1][0] = si_[0][1]; si_[2][0] = si_[0][2]; si_[2][1] = si_[1][2];
        float logdetS = (float)log(det);

        // K = PHt * Sinv [6x3]
        float kf[6][3];
#pragma unroll
        for (int i = 0; i < 6; i++)
#pragma unroll
            for (int l = 0; l < 3; l++) {
                double acc = 0.0;
#pragma unroll
                for (int k = 0; k < 3; k++) acc += (double)PHt[i][k] * si_[k][l];
                kf[i][l] = (float)acc;
            }

        // post_cov = P - (K H) P -> staged in LDS for coalesced write
#pragma unroll
        for (int i = 0; i < 6; i++) {
            float kh0 = kf[i][0] * h[0][0] + kf[i][1] * h[1][0] + kf[i][2] * h[2][0];
            float kh1 = kf[i][0] * h[0][1] + kf[i][1] * h[1][1] + kf[i][2] * h[2][1];
            float kh2 = kf[i][0] * h[0][2] + kf[i][1] * h[1][2] + kf[i][2] * h[2][2];
#pragma unroll
            for (int j = 0; j < 6; j++) {
                scov[t * 36 + i * 6 + j] =
                    sP[i*6+j] - (kh0 * sP[0*6+j] + kh1 * sP[1*6+j] + kh2 * sP[2*6+j]);
            }
        }

        float cterm = (float)LOGPD + logf(wts[n]) - 0.5f * (logdetS + 3.0f * (float)LOG2PI);

        // SoA params: q[0..17]=K (i*3+k), q[18..23]=si(00,01,02,11,12,22),
        // q[24..26]=yb, q[27]=cterm. param4[i][n] coalesced.
        f32x4 qv;
        qv = (f32x4){kf[0][0], kf[0][1], kf[0][2], kf[1][0]}; param4[0*N_COMP + n] = qv;
        qv = (f32x4){kf[1][1], kf[1][2], kf[2][0], kf[2][1]}; param4[1*N_COMP + n] = qv;
        qv = (f32x4){kf[2][2], kf[3][0], kf[3][1], kf[3][2]}; param4[2*N_COMP + n] = qv;
        qv = (f32x4){kf[4][0], kf[4][1], kf[4][2], kf[5][0]}; param4[3*N_COMP + n] = qv;
        qv = (f32x4){kf[5][1], kf[5][2], (float)si_[0][0], (float)si_[0][1]}; param4[4*N_COMP + n] = qv;
        qv = (f32x4){(float)si_[0][2], (float)si_[1][1], (float)si_[1][2], (float)si_[2][2]}; param4[5*N_COMP + n] = qv;
        qv = (f32x4){yb0, yb1, yb2, cterm}; param4[6*N_COMP + n] = qv;
    }
    __syncthreads();

    // Coalesced float4 write of this block's cov rows to the m=0 slice.
    int nvalid = min(64, N_COMP - blockIdx.x * 64);
    int nf4 = nvalid * 9;                         // 36 floats = 9 f4 per comp
    f32x4* dst = (f32x4*)(out3 + (size_t)blockIdx.x * 64 * 36);
    const f32x4* s4 = (const f32x4*)scov;
    for (int j = t; j < nf4; j += 64) dst[j] = s4[j];
}

// ---------------------------------------------------------------------------
// Kernel 3: heterogeneous grid (79+176, 64).
//  * x <  79 : compB job for (bx=x, m=y) — per-(m,n) update, coalesced SoA
//              param reads, LDS-transposed out1 writes, fused block lse.
//  * x >= 79 : bcast job — copy 16 KB chunk (x-79) of cov slice 0 -> slice y
//              (y>=1; destination-linear, plain cached stores; identical to
//              the proven standalone bcast block, co-scheduled so the pure
//              write stream overlaps compB's compute).
// bcast depends only on compA's slice-0 write (previous kernel) — safe.
// ---------------------------------------------------------------------------
__global__ __launch_bounds__(256) void compB_kernel(
    const float* __restrict__ pm, const float* __restrict__ meas,
    const f32x4* __restrict__ param4,
    float* __restrict__ out1, float* __restrict__ ldt,
    float2* __restrict__ lsepart, float* __restrict__ out3)
{
    int t = threadIdx.x;
    int bx = blockIdx.x, m = blockIdx.y;

    if (bx >= NBLK_N) {
        // ---- bcast job ----
        if (m >= 1) {
            int base = (bx - NBLK_N) * CHUNK_F4;
            const f32x4* src = (const f32x4*)out3;
            f32x4* d = (f32x4*)out3 + (size_t)m * COV_F4;
#pragma unroll
            for (int k = 0; k < 4; k++) {
                int j = base + k * 256 + t;
                if (j < COV_F4) d[j] = src[j];
            }
        }
        return;
    }

    int n = bx * 256 + t;
    bool valid = n < N_COMP;

    float z0 = meas[m * 3 + 0];
    float z1 = meas[m * 3 + 1];
    float z2 = meas[m * 3 + 2];

    float p0 = 0.f, p1 = 0.f, p2 = 0.f, p3 = 0.f, p4 = 0.f, p5 = 0.f;
    float lv = 0.f;
    if (valid) {
        float q[28];
#pragma unroll
        for (int i = 0; i < 7; i++) {
            f32x4 v = param4[i * N_COMP + n];
            q[i*4+0] = v.x; q[i*4+1] = v.y; q[i*4+2] = v.z; q[i*4+3] = v.w;
        }
        float r0 = q[24] - z0;
        float r1 = q[25] - z1;
        float r2 = q[26] - z2;

        float maha = q[18] * r0 * r0 + q[21] * r1 * r1 + q[23] * r2 * r2
                   + 2.f * (q[19] * r0 * r1 + q[20] * r0 * r2 + q[22] * r1 * r2);
        lv = q[27] - 0.5f * maha;

        const float2* pmv = (const float2*)(pm + (size_t)n * 6);
        float2 m01 = pmv[0], m23 = pmv[1], m45 = pmv[2];
        p0 = m01.x - (q[0]  * r0 + q[1]  * r1 + q[2]  * r2);
        p1 = m01.y - (q[3]  * r0 + q[4]  * r1 + q[5]  * r2);
        p2 = m23.x - (q[6]  * r0 + q[7]  * r1 + q[8]  * r2);
        p3 = m23.y - (q[9]  * r0 + q[10] * r1 + q[11] * r2);
        p4 = m45.x - (q[12] * r0 + q[13] * r1 + q[14] * r2);
        p5 = m45.y - (q[15] * r0 + q[16] * r1 + q[17] * r2);

        ldt[(size_t)m * N_COMP + n] = lv;
    }

    // --- coalesced out1 write via LDS transpose ---
    __shared__ float sOut[256 * 6];
    if (valid) {
        sOut[t * 6 + 0] = p0; sOut[t * 6 + 1] = p1; sOut[t * 6 + 2] = p2;
        sOut[t * 6 + 3] = p3; sOut[t * 6 + 4] = p4; sOut[t * 6 + 5] = p5;
    }
    __syncthreads();
    int nvalid = min(256, N_COMP - bx * 256);
    int nf4 = nvalid * 6 / 4;                    // 1536/4=384 or 192/4=48
    f32x4* o4 = (f32x4*)(out1 + ((size_t)m * N_COMP + (size_t)bx * 256) * 6);
    const f32x4* s4 = (const f32x4*)sOut;
    for (int j = t; j < nf4; j += 256) o4[j] = s4[j];

    // --- fused online logsumexp partial over this block's 256 values ---
    float mx = valid ? lv : -1e30f;
    float s  = valid ? 1.0f : 0.0f;              // exp(lv - mx) = 1
    for (int off = 32; off; off >>= 1) {
        float om = __shfl_down(mx, off);
        float os = __shfl_down(s, off);
        float nm = fmaxf(mx, om);
        s = s * expf(mx - nm) + os * expf(om - nm);
        mx = nm;
    }
    __shared__ float sRm[4], sRs[4];
    int wid = t >> 6, lane = t & 63;
    if (lane == 0) { sRm[wid] = mx; sRs[wid] = s; }
    __syncthreads();
    if (t == 0) {
        float M = sRm[0], S = sRs[0];
#pragma unroll
        for (int w = 1; w < 4; w++) {
            float nm = fmaxf(M, sRm[w]);
            S = S * expf(M - nm) + sRs[w] * expf(sRm[w] - nm);
            M = nm;
        }
        lsepart[(size_t)m * NBLK_N + bx] = make_float2(M, S);
    }
}

// ---------------------------------------------------------------------------
// Kernel 4: combine per-block lse partials inline (redundantly per block,
// tiny) and normalize the weight row. Full grid: (79, 64) x 256.
// ---------------------------------------------------------------------------
__global__ __launch_bounds__(256) void wt2_kernel(float* __restrict__ out2,
                                                  const float2* __restrict__ lsepart)
{
    int t = threadIdx.x;
    int bx = blockIdx.x, m = blockIdx.y;

    float mx = -1e30f, s = 0.f;
    if (t < 64) {
        float2 p = lsepart[(size_t)m * NBLK_N + t];
        mx = p.x; s = p.y;
        if (t + 64 < NBLK_N) {
            float2 q = lsepart[(size_t)m * NBLK_N + t + 64];
            float nm = fmaxf(mx, q.x);
            s = s * expf(mx - nm) + q.y * expf(q.x - nm);
            mx = nm;
        }
    }
    for (int off = 32; off; off >>= 1) {
        float om = __shfl_down(mx, off);
        float os = __shfl_down(s, off);
        float nm = fmaxf(mx, om);
        s = s * expf(mx - nm) + os * expf(om - nm);
        mx = nm;
    }
    __shared__ float sld;
    if (t == 0) {
        double ls = (double)mx + log((double)s);       // log_sum_detection
        sld = (float)log(CLUTTER + exp(ls));           // log_denominator
    }
    __syncthreads();
    float ld = sld;

    int n = bx * 256 + t;
    if (n < N_COMP) {
        size_t idx = (size_t)m * N_COMP + n;
        out2[idx] = expf(out2[idx] - ld);
    }
}

// ---------------------------------------------------------------------------
extern "C" void kernel_launch(void* const* d_in, const int* in_sizes, int n_in,
                              void* d_out, int out_size, void* d_ws, size_t ws_size,
                              hipStream_t stream)
{
    const float* pm   = (const float*)d_in[0];   // [20000, 6]
    const float* wts  = (const float*)d_in[1];   // [20000]
    const float* meas = (const float*)d_in[2];   // [64, 3]
    const float* R    = (const float*)d_in[3];   // [3, 3]
    // d_in[4] = measurements_mask: all-true by construction -> no-op.

    float* out1 = (float*)d_out;                            // ensemble [64,20000,6]
    float* out2 = out1 + (size_t)N_MEAS * N_COMP * 6;       // weights  [64,20000]
    float* out3 = out2 + (size_t)N_MEAS * N_COMP;           // covs     [64,20000,36]

    double* partials = (double*)d_ws;                        // 80*27 doubles (17.3 KB)
    float*  pad      = (float*)(partials + NBLK_STATS * 27);
    f32x4*  param4   = (f32x4*)(pad + 64);                   // 7*20000 f4 (2.24 MB), 16B-aligned
    float2* lsepart  = (float2*)(param4 + 7 * N_COMP);       // 64*79 float2

    double bw = pow(4.0 / ((double)N_COMP * 8.0), 0.2);      // (4/(N(D+2)))^(2/(D+4))
    Loc6 bwloc;
    for (int k = 0; k < 6; k++)
        bwloc.v[k] = bw * exp(-(double)(k * k) / 18.0);      // bw * loc(|i-j|)

    stats1_kernel<<<NBLK_STATS, 256, 0, stream>>>(pm, partials);
    compA_kernel<<<(N_COMP + 63) / 64, 64, 0, stream>>>(
        pm, wts, R, partials, bwloc, param4, out3);
    compB_kernel<<<dim3(NBLK_N + NCHUNK, N_MEAS), 256, 0, stream>>>(
        pm, meas, param4, out1, out2, lsepart, out3);
    wt2_kernel<<<dim3(NBLK_N, N_MEAS), 256, 0, stream>>>(out2, lsepart);
}

// Round 9
// 245.458 us; speedup vs baseline: 1.1714x; 1.1714x over previous
//
#include <hip/hip_runtime.h>
#include <math.h>

#define N_COMP 20000
#define N_MEAS 64
#define LOG2PI 1.8378770664093453
#define LOGPD  (-0.020202707317519466)   /* log(0.98) */
#define CLUTTER 1e-4
#define NBLK_STATS 80                    /* 80*256 = 20480 >= 20000 */
#define NBLK_N 79                        /* ceil(20000/256) */
#define COV_F4 (N_COMP * 36 / 4)         /* 180000 float4 per measurement cov slice */
#define CHUNK_F4 1024                    /* 16 KB dest run per block */
#define NCHUNK ((COV_F4 + CHUNK_F4 - 1) / CHUNK_F4)   /* 176 */

typedef float f32x4 __attribute__((ext_vector_type(4)));

struct Loc6 { double v[6]; };            // bw * exp(-k^2/18), k=0..5 (host-computed)

// ---------------------------------------------------------------------------
// Kernel 1: per-block partial sums for empirical covariance (double).
// ---------------------------------------------------------------------------
__global__ __launch_bounds__(256) void stats1_kernel(const float* __restrict__ pm,
                                                     double* __restrict__ partials)
{
    int n = blockIdx.x * 256 + threadIdx.x;
    float v[6] = {0.f, 0.f, 0.f, 0.f, 0.f, 0.f};
    if (n < N_COMP) {
        const float2* p2 = (const float2*)(pm + (size_t)n * 6);
        float2 a = p2[0], b = p2[1], c = p2[2];
        v[0] = a.x; v[1] = a.y; v[2] = b.x; v[3] = b.y; v[4] = c.x; v[5] = c.y;
    }
    double s[27];
#pragma unroll
    for (int i = 0; i < 6; i++) s[i] = (double)v[i];
    int idx = 6;
#pragma unroll
    for (int i = 0; i < 6; i++)
#pragma unroll
        for (int j = i; j < 6; j++) s[idx++] = (double)v[i] * (double)v[j];

#pragma unroll
    for (int i = 0; i < 27; i++)
        for (int off = 32; off; off >>= 1) s[i] += __shfl_down(s[i], off);

    __shared__ double sd[27 * 4];
    int wid = threadIdx.x >> 6, lane = threadIdx.x & 63;
    if (lane == 0)
#pragma unroll
        for (int i = 0; i < 27; i++) sd[i * 4 + wid] = s[i];
    __syncthreads();
    if (threadIdx.x < 27) {
        int i = threadIdx.x;
        partials[(size_t)blockIdx.x * 27 + i] =
            sd[i * 4] + sd[i * 4 + 1] + sd[i * 4 + 2] + sd[i * 4 + 3];
    }
}

// ---------------------------------------------------------------------------
// Kernel 2: per-component linearization, with stats2 folded in: each block
// redundantly reduces the 80x27 partials (17 KB, L2-hit after first touch)
// and computes the localized bandwidth-scaled P inline. Writes SoA params
// (param4[i][n], coalesced) and the m=0 covariance slice via LDS transpose.
// ---------------------------------------------------------------------------
__global__ __launch_bounds__(64) void compA_kernel(
    const float* __restrict__ pm, const float* __restrict__ wts,
    const float* __restrict__ R, const double* __restrict__ partials,
    Loc6 bwloc, f32x4* __restrict__ param4, float* __restrict__ out3)
{
    __shared__ float sP[36];
    __shared__ float sR[9];
    __shared__ double tot[27];
    __shared__ float scov[64 * 36];
    int t = threadIdx.x;
    if (t < 27) {
        double a = 0.0;
        for (int b = 0; b < NBLK_STATS; b++) a += partials[(size_t)b * 27 + t];
        tot[t] = a;
    } else if (t >= 32 && t < 41) {
        sR[t - 32] = R[t - 32];
    }
    __syncthreads();
    if (t == 0) {
        double mean[6];
        for (int i = 0; i < 6; i++) mean[i] = tot[i] / (double)N_COMP;
        int idx = 6;
        for (int i = 0; i < 6; i++)
            for (int j = i; j < 6; j++) {
                double c = (tot[idx++] - (double)N_COMP * mean[i] * mean[j]) /
                           (double)(N_COMP - 1);
                float pv = (float)(c * bwloc.v[j - i]);   // bw * cov * loc(|i-j|)
                sP[i * 6 + j] = pv;
                sP[j * 6 + i] = pv;
            }
    }
    __syncthreads();

    int n = blockIdx.x * 64 + t;
    bool valid = n < N_COMP;

    if (valid) {
        const float2* pmv = (const float2*)(pm + (size_t)n * 6);
        float2 m01 = pmv[0], m23 = pmv[1];
        float x = m01.x, y = m01.y, z = m23.x;
        float rxy2 = x * x + y * y;
        float r2 = rxy2 + z * z;
        float r = sqrtf(r2);
        float rxy = sqrtf(rxy2);

        float yb0 = r;
        float yb1 = atan2f(y, x);
        float yb2 = asinf(z / r);

        // Analytic Jacobian of h (position columns only)
        float h[3][3];
        h[0][0] = x / r;      h[0][1] = y / r;      h[0][2] = z / r;
        h[1][0] = -y / rxy2;  h[1][1] = x / rxy2;   h[1][2] = 0.f;
        float inv_r2rxy = 1.f / (r2 * rxy);
        h[2][0] = -x * z * inv_r2rxy;
        h[2][1] = -y * z * inv_r2rxy;
        h[2][2] = rxy / r2;

        // PHt[i][k] = sum_j P[i][j] * H[k][j]
        float PHt[6][3];
#pragma unroll
        for (int i = 0; i < 6; i++)
#pragma unroll
            for (int k = 0; k < 3; k++)
                PHt[i][k] = sP[i*6+0] * h[k][0] + sP[i*6+1] * h[k][1] + sP[i*6+2] * h[k][2];

        // S = H*PHt + R; invert 3x3 in double (condition ~6e6)
        double Sm[3][3];
#pragma unroll
        for (int k = 0; k < 3; k++)
#pragma unroll
            for (int l = 0; l < 3; l++) {
                double acc = (double)sR[k * 3 + l];
#pragma unroll
                for (int i = 0; i < 3; i++) acc += (double)h[k][i] * (double)PHt[i][l];
                Sm[k][l] = acc;
            }
        double a = Sm[0][0], b = Sm[0][1], c = Sm[0][2];
        double d = Sm[1][1], e = Sm[1][2], f = Sm[2][2];
        double A = d * f - e * e;
        double B = c * e - b * f;
        double C = b * e - c * d;
        double det = a * A + b * B + c * C;
        double invdet = 1.0 / det;
        double si_[3][3];
        si_[0][0] = A * invdet;  si_[0][1] = B * invdet;  si_[0][2] = C * invdet;
        si_[1][1] = (a * f - c * c) * invdet;
        si_[1][2] = (b * c - a * e) * invdet;
        si_[2][2] = (a * d - b * b) * invdet;
        si_[1][0] = si_[0][1]; si_[2][0] = si_[0][2]; si_[2][1] = si_[1][2];
        float logdetS = (float)log(det);

        // K = PHt * Sinv [6x3]
        float kf[6][3];
#pragma unroll
        for (int i = 0; i < 6; i++)
#pragma unroll
            for (int l = 0; l < 3; l++) {
                double acc = 0.0;
#pragma unroll
                for (int k = 0; k < 3; k++) acc += (double)PHt[i][k] * si_[k][l];
                kf[i][l] = (float)acc;
            }

        // post_cov = P - (K H) P -> staged in LDS for coalesced write
#pragma unroll
        for (int i = 0; i < 6; i++) {
            float kh0 = kf[i][0] * h[0][0] + kf[i][1] * h[1][0] + kf[i][2] * h[2][0];
            float kh1 = kf[i][0] * h[0][1] + kf[i][1] * h[1][1] + kf[i][2] * h[2][1];
            float kh2 = kf[i][0] * h[0][2] + kf[i][1] * h[1][2] + kf[i][2] * h[2][2];
#pragma unroll
            for (int j = 0; j < 6; j++) {
                scov[t * 36 + i * 6 + j] =
                    sP[i*6+j] - (kh0 * sP[0*6+j] + kh1 * sP[1*6+j] + kh2 * sP[2*6+j]);
            }
        }

        float cterm = (float)LOGPD + logf(wts[n]) - 0.5f * (logdetS + 3.0f * (float)LOG2PI);

        // SoA params: q[0..17]=K (i*3+k), q[18..23]=si(00,01,02,11,12,22),
        // q[24..26]=yb, q[27]=cterm. param4[i][n] coalesced.
        f32x4 qv;
        qv = (f32x4){kf[0][0], kf[0][1], kf[0][2], kf[1][0]}; param4[0*N_COMP + n] = qv;
        qv = (f32x4){kf[1][1], kf[1][2], kf[2][0], kf[2][1]}; param4[1*N_COMP + n] = qv;
        qv = (f32x4){kf[2][2], kf[3][0], kf[3][1], kf[3][2]}; param4[2*N_COMP + n] = qv;
        qv = (f32x4){kf[4][0], kf[4][1], kf[4][2], kf[5][0]}; param4[3*N_COMP + n] = qv;
        qv = (f32x4){kf[5][1], kf[5][2], (float)si_[0][0], (float)si_[0][1]}; param4[4*N_COMP + n] = qv;
        qv = (f32x4){(float)si_[0][2], (float)si_[1][1], (float)si_[1][2], (float)si_[2][2]}; param4[5*N_COMP + n] = qv;
        qv = (f32x4){yb0, yb1, yb2, cterm}; param4[6*N_COMP + n] = qv;
    }
    __syncthreads();

    // Coalesced float4 write of this block's cov rows to the m=0 slice.
    int nvalid = min(64, N_COMP - blockIdx.x * 64);
    int nf4 = nvalid * 9;                         // 36 floats = 9 f4 per comp
    f32x4* dst = (f32x4*)(out3 + (size_t)blockIdx.x * 64 * 36);
    const f32x4* s4 = (const f32x4*)scov;
    for (int j = t; j < nf4; j += 64) dst[j] = s4[j];
}

// ---------------------------------------------------------------------------
// Kernel 3: one thread per (m, n). Coalesced SoA param reads; LDS-transposed
// coalesced out1 writes; fused block-level online logsumexp partial.
// ---------------------------------------------------------------------------
__global__ __launch_bounds__(256) void compB_kernel(
    const float* __restrict__ pm, const float* __restrict__ meas,
    const f32x4* __restrict__ param4,
    float* __restrict__ out1, float* __restrict__ ldt,
    float2* __restrict__ lsepart)
{
    int t = threadIdx.x;
    int bx = blockIdx.x, m = blockIdx.y;
    int n = bx * 256 + t;
    bool valid = n < N_COMP;

    float z0 = meas[m * 3 + 0];
    float z1 = meas[m * 3 + 1];
    float z2 = meas[m * 3 + 2];

    float p0 = 0.f, p1 = 0.f, p2 = 0.f, p3 = 0.f, p4 = 0.f, p5 = 0.f;
    float lv = 0.f;
    if (valid) {
        float q[28];
#pragma unroll
        for (int i = 0; i < 7; i++) {
            f32x4 v = param4[i * N_COMP + n];
            q[i*4+0] = v.x; q[i*4+1] = v.y; q[i*4+2] = v.z; q[i*4+3] = v.w;
        }
        float r0 = q[24] - z0;
        float r1 = q[25] - z1;
        float r2 = q[26] - z2;

        float maha = q[18] * r0 * r0 + q[21] * r1 * r1 + q[23] * r2 * r2
                   + 2.f * (q[19] * r0 * r1 + q[20] * r0 * r2 + q[22] * r1 * r2);
        lv = q[27] - 0.5f * maha;

        const float2* pmv = (const float2*)(pm + (size_t)n * 6);
        float2 m01 = pmv[0], m23 = pmv[1], m45 = pmv[2];
        p0 = m01.x - (q[0]  * r0 + q[1]  * r1 + q[2]  * r2);
        p1 = m01.y - (q[3]  * r0 + q[4]  * r1 + q[5]  * r2);
        p2 = m23.x - (q[6]  * r0 + q[7]  * r1 + q[8]  * r2);
        p3 = m23.y - (q[9]  * r0 + q[10] * r1 + q[11] * r2);
        p4 = m45.x - (q[12] * r0 + q[13] * r1 + q[14] * r2);
        p5 = m45.y - (q[15] * r0 + q[16] * r1 + q[17] * r2);

        ldt[(size_t)m * N_COMP + n] = lv;
    }

    // --- coalesced out1 write via LDS transpose ---
    __shared__ float sOut[256 * 6];
    if (valid) {
        sOut[t * 6 + 0] = p0; sOut[t * 6 + 1] = p1; sOut[t * 6 + 2] = p2;
        sOut[t * 6 + 3] = p3; sOut[t * 6 + 4] = p4; sOut[t * 6 + 5] = p5;
    }
    __syncthreads();
    int nvalid = min(256, N_COMP - bx * 256);
    int nf4 = nvalid * 6 / 4;                    // 1536/4=384 or 192/4=48
    f32x4* o4 = (f32x4*)(out1 + ((size_t)m * N_COMP + (size_t)bx * 256) * 6);
    const f32x4* s4 = (const f32x4*)sOut;
    for (int j = t; j < nf4; j += 256) o4[j] = s4[j];

    // --- fused online logsumexp partial over this block's 256 values ---
    float mx = valid ? lv : -1e30f;
    float s  = valid ? 1.0f : 0.0f;              // exp(lv - mx) = 1
    for (int off = 32; off; off >>= 1) {
        float om = __shfl_down(mx, off);
        float os = __shfl_down(s, off);
        float nm = fmaxf(mx, om);
        s = s * expf(mx - nm) + os * expf(om - nm);
        mx = nm;
    }
    __shared__ float sRm[4], sRs[4];
    int wid = t >> 6, lane = t & 63;
    if (lane == 0) { sRm[wid] = mx; sRs[wid] = s; }
    __syncthreads();
    if (t == 0) {
        float M = sRm[0], S = sRs[0];
#pragma unroll
        for (int w = 1; w < 4; w++) {
            float nm = fmaxf(M, sRm[w]);
            S = S * expf(M - nm) + sRs[w] * expf(sRm[w] - nm);
            M = nm;
        }
        lsepart[(size_t)m * NBLK_N + bx] = make_float2(M, S);
    }
}

// ---------------------------------------------------------------------------
// Kernel 4: fused tail — grid (176, 64) x 256.
//  * bcast job (y>=1):   copy 16 KB chunk x of cov slice 0 -> slice y
//                        (destination-linear, plain cached stores).
//  * wt2 job (x<79):     combine lse partials for row m=y (redundant, tiny)
//                        and normalize weight chunk (bx=x, m=y).
// The two jobs touch disjoint outputs (out3 vs out2) and are independent.
// ---------------------------------------------------------------------------
__global__ __launch_bounds__(256) void tail_kernel(float* __restrict__ out2,
                                                   const float2* __restrict__ lsepart,
                                                   const f32x4* __restrict__ src,
                                                   f32x4* __restrict__ dst)
{
    int t = threadIdx.x;
    int bx = blockIdx.x, m = blockIdx.y;

    // ---- bcast part ----
    if (m >= 1) {
        int base = bx * CHUNK_F4;
        f32x4* d = dst + (size_t)m * COV_F4;
#pragma unroll
        for (int k = 0; k < 4; k++) {
            int j = base + k * 256 + t;
            if (j < COV_F4) d[j] = src[j];
        }
    }

    // ---- wt2 part ----
    if (bx < NBLK_N) {
        float mx = -1e30f, s = 0.f;
        if (t < 64) {
            float2 p = lsepart[(size_t)m * NBLK_N + t];
            mx = p.x; s = p.y;
            if (t + 64 < NBLK_N) {
                float2 q = lsepart[(size_t)m * NBLK_N + t + 64];
                float nm = fmaxf(mx, q.x);
                s = s * expf(mx - nm) + q.y * expf(q.x - nm);
                mx = nm;
            }
        }
        for (int off = 32; off; off >>= 1) {
            float om = __shfl_down(mx, off);
            float os = __shfl_down(s, off);
            float nm = fmaxf(mx, om);
            s = s * expf(mx - nm) + os * expf(om - nm);
            mx = nm;
        }
        __shared__ float sld;
        if (t == 0) {
            double ls = (double)mx + log((double)s);       // log_sum_detection
            sld = (float)log(CLUTTER + exp(ls));           // log_denominator
        }
        __syncthreads();
        float ld = sld;

        int n = bx * 256 + t;
        if (n < N_COMP) {
            size_t idx = (size_t)m * N_COMP + n;
            out2[idx] = expf(out2[idx] - ld);
        }
    }
}

// ---------------------------------------------------------------------------
extern "C" void kernel_launch(void* const* d_in, const int* in_sizes, int n_in,
                              void* d_out, int out_size, void* d_ws, size_t ws_size,
                              hipStream_t stream)
{
    const float* pm   = (const float*)d_in[0];   // [20000, 6]
    const float* wts  = (const float*)d_in[1];   // [20000]
    const float* meas = (const float*)d_in[2];   // [64, 3]
    const float* R    = (const float*)d_in[3];   // [3, 3]
    // d_in[4] = measurements_mask: all-true by construction -> no-op.

    float* out1 = (float*)d_out;                            // ensemble [64,20000,6]
    float* out2 = out1 + (size_t)N_MEAS * N_COMP * 6;       // weights  [64,20000]
    float* out3 = out2 + (size_t)N_MEAS * N_COMP;           // covs     [64,20000,36]

    double* partials = (double*)d_ws;                        // 80*27 doubles (17.3 KB)
    float*  pad      = (float*)(partials + NBLK_STATS * 27);
    f32x4*  param4   = (f32x4*)(pad + 64);                   // 7*20000 f4 (2.24 MB), 16B-aligned
    float2* lsepart  = (float2*)(param4 + 7 * N_COMP);       // 64*79 float2

    double bw = pow(4.0 / ((double)N_COMP * 8.0), 0.2);      // (4/(N(D+2)))^(2/(D+4))
    Loc6 bwloc;
    for (int k = 0; k < 6; k++)
        bwloc.v[k] = bw * exp(-(double)(k * k) / 18.0);      // bw * loc(|i-j|)

    stats1_kernel<<<NBLK_STATS, 256, 0, stream>>>(pm, partials);
    compA_kernel<<<(N_COMP + 63) / 64, 64, 0, stream>>>(
        pm, wts, R, partials, bwloc, param4, out3);
    compB_kernel<<<dim3(NBLK_N, N_MEAS), 256, 0, stream>>>(
        pm, meas, param4, out1, out2, lsepart);
    tail_kernel<<<dim3(NCHUNK, N_MEAS), 256, 0, stream>>>(
        out2, lsepart, (const f32x4*)out3, (f32x4*)out3);
}